// Round 7
// baseline (337.253 us; speedup 1.0000x reference)
//
#include <hip/hip_runtime.h>
#include <cmath>

#define LRELU(e) ((e) > 0.f ? (e) : 0.2f*(e))

typedef __bf16 bf16x8 __attribute__((ext_vector_type(8)));
typedef float  f32x4  __attribute__((ext_vector_type(4)));

// bf16 (packed in a dword) -> f32 by bit ops, no cvt needed
__device__ __forceinline__ float bflo(unsigned u) { return __uint_as_float(u << 16); }
__device__ __forceinline__ float bfhi(unsigned u) { return __uint_as_float(u & 0xffff0000u); }
__device__ __forceinline__ unsigned packbf(float a, float b) {
  __bf16 x = (__bf16)a, y = (__bf16)b;
  unsigned short ux = *(unsigned short*)&x, uy = *(unsigned short*)&y;
  return ((unsigned)uy << 16) | ux;
}

// ---------------- CSR build ----------------
__global__ void k_hist(const int* __restrict__ dst, int* __restrict__ deg, int E) {
  int e = blockIdx.x*blockDim.x + threadIdx.x;
  if (e < E) atomicAdd(&deg[dst[e]], 1);
}

__global__ __launch_bounds__(1024) void k_scan1(const int* __restrict__ deg,
                        int* __restrict__ row_start, int* __restrict__ bsums, int n) {
  __shared__ int sm[1024];
  int t = threadIdx.x;
  int i = blockIdx.x*1024 + t;
  sm[t] = (i < n) ? deg[i] : 0;
  __syncthreads();
  for (int off = 1; off < 1024; off <<= 1) {
    int v = (t >= off) ? sm[t-off] : 0;
    __syncthreads();
    sm[t] += v;
    __syncthreads();
  }
  if (i < n) row_start[i+1] = sm[t];
  if (t == 1023) bsums[blockIdx.x] = sm[1023];
  if (i == 0) row_start[0] = 0;
}

__global__ void k_scan2(int* __restrict__ bsums, int nb) {
  __shared__ int sm[64];
  int t = threadIdx.x;
  sm[t] = (t < nb) ? bsums[t] : 0;
  __syncthreads();
  for (int off = 1; off < 64; off <<= 1) {
    int v = (t >= off) ? sm[t-off] : 0;
    __syncthreads();
    sm[t] += v;
    __syncthreads();
  }
  if (t < nb) bsums[t] = (t == 0) ? 0 : sm[t-1];
}

__global__ __launch_bounds__(1024) void k_scan3(int* __restrict__ row_start,
                        const int* __restrict__ bsums, int n) {
  int i = blockIdx.x*1024 + threadIdx.x;
  if (i < n) row_start[i+1] += bsums[blockIdx.x];
}

__global__ void k_fill(const int* __restrict__ src, const int* __restrict__ dst,
                       const int* __restrict__ row_start, int* __restrict__ cursor,
                       int* __restrict__ csr_src, int E) {
  int e = blockIdx.x*blockDim.x + threadIdx.x;
  if (e < E) {
    int d = dst[e];
    int pos = atomicAdd(&cursor[d], 1);
    csr_src[row_start[d] + pos] = src[e];
  }
}

// ---------------- weight transposes to bf16 ----------------
__global__ void k_w1t(const float* __restrict__ W1, __bf16* __restrict__ W1T) {
  int idx = blockIdx.x*blockDim.x + threadIdx.x;   // n*512 + k
  if (idx < 256*512) {
    int n = idx >> 9, k = idx & 511;
    W1T[idx] = (__bf16)W1[k*256 + n];
  }
}

__global__ void k_w2t(const float* __restrict__ W2, __bf16* __restrict__ W2T) {
  int idx = blockIdx.x*blockDim.x + threadIdx.x;   // n*256 + k
  if (idx < 64*256) {
    int n = idx >> 8, k = idx & 255;
    W2T[idx] = (__bf16)W2[k*64 + n];
  }
}

// ---------------- GEMM1 (bf16 MFMA) + fused lr1, bf16 feat1 out ----------------
// feat1[N,256] = x[N,512] @ W1[512,256]. BM=64, BN=256 (x read ONCE), BK=32.
// 4 waves (2x2): wave tile 32 rows x 128 cols (= 2 heads).
__global__ __launch_bounds__(256) void k_gemm1(const float* __restrict__ x,
                        const __bf16* __restrict__ W1T, __bf16* __restrict__ feat1,
                        const float* __restrict__ al1, const float* __restrict__ ar1,
                        float* __restrict__ el1, float* __restrict__ er1, int M) {
  const int K = 512, Nn = 256;
  __shared__ __bf16 A_sm[64][40];
  __shared__ __bf16 B_sm[256][40];
  int tid = threadIdx.x;
  int lane = tid & 63, wid = tid >> 6;
  int wm = wid >> 1, wn = wid & 1;
  int bm = blockIdx.x * 64;

  int srow = tid >> 2;            // 0..63
  int scol = (tid & 3) * 8;       // 0,8,16,24

  f32x4 acc[2][8];
  #pragma unroll
  for (int i = 0; i < 2; ++i)
    #pragma unroll
    for (int j = 0; j < 8; ++j) acc[i][j] = (f32x4){0.f,0.f,0.f,0.f};

  for (int k0 = 0; k0 < K; k0 += 32) {
    // stage A: x[bm+srow][k0+scol..+8] f32 -> bf16
    {
      bf16x8 v;
      if (bm + srow < M) {
        const float* xp = x + (size_t)(bm+srow)*K + k0 + scol;
        float4 f0 = *(const float4*)xp;
        float4 f1 = *(const float4*)(xp+4);
        v[0]=(__bf16)f0.x; v[1]=(__bf16)f0.y; v[2]=(__bf16)f0.z; v[3]=(__bf16)f0.w;
        v[4]=(__bf16)f1.x; v[5]=(__bf16)f1.y; v[6]=(__bf16)f1.z; v[7]=(__bf16)f1.w;
      } else {
        v = (bf16x8){};
      }
      *(bf16x8*)&A_sm[srow][scol] = v;
    }
    // stage B: W1T rows 0..255
    #pragma unroll
    for (int p = 0; p < 4; ++p) {
      int row = p*64 + srow;
      *(bf16x8*)&B_sm[row][scol] = *(const bf16x8*)(W1T + (size_t)row*K + k0 + scol);
    }
    __syncthreads();
    bf16x8 af[2], bfr[8];
    #pragma unroll
    for (int mf = 0; mf < 2; ++mf)
      af[mf] = *(const bf16x8*)&A_sm[wm*32 + mf*16 + (lane&15)][(lane>>4)*8];
    #pragma unroll
    for (int nf = 0; nf < 8; ++nf)
      bfr[nf] = *(const bf16x8*)&B_sm[wn*128 + nf*16 + (lane&15)][(lane>>4)*8];
    #pragma unroll
    for (int mf = 0; mf < 2; ++mf)
      #pragma unroll
      for (int nf = 0; nf < 8; ++nf)
        acc[mf][nf] = __builtin_amdgcn_mfma_f32_16x16x32_bf16(af[mf], bfr[nf], acc[mf][nf], 0, 0, 0);
    __syncthreads();
  }
  // attn weight slices: index == output column
  float al_r[8], ar_r[8];
  #pragma unroll
  for (int nf = 0; nf < 8; ++nf) {
    int n = wn*128 + nf*16 + (lane&15);
    al_r[nf] = al1[n];
    ar_r[nf] = ar1[n];
  }
  #pragma unroll
  for (int mf = 0; mf < 2; ++mf) {
    #pragma unroll
    for (int j = 0; j < 4; ++j) {
      int m = bm + wm*32 + mf*16 + (lane>>4)*4 + j;
      float pl[2] = {0.f, 0.f}, pr[2] = {0.f, 0.f};
      #pragma unroll
      for (int nf = 0; nf < 8; ++nf) {
        float val = acc[mf][nf][j];
        int g = nf >> 2;
        pl[g] = fmaf(val, al_r[nf], pl[g]);
        pr[g] = fmaf(val, ar_r[nf], pr[g]);
        if (m < M) {
          int n = wn*128 + nf*16 + (lane&15);
          feat1[(size_t)m*Nn + n] = (__bf16)val;
        }
      }
      #pragma unroll
      for (int g = 0; g < 2; ++g) {
        #pragma unroll
        for (int s = 8; s >= 1; s >>= 1) {
          pl[g] += __shfl_xor(pl[g], s);
          pr[g] += __shfl_xor(pr[g], s);
        }
      }
      if ((lane & 15) == 0 && m < M) {
        el1[m*4 + wn*2 + 0] = pl[0];
        er1[m*4 + wn*2 + 0] = pr[0];
        el1[m*4 + wn*2 + 1] = pl[1];
        er1[m*4 + wn*2 + 1] = pr[1];
      }
    }
  }
}

// ---------------- GEMM2 (bf16 MFMA): feat2[N,64] = h1[N,256] @ W2[256,64] -----
// BM=128, BN=64, BK=32; bf16 output.
__global__ __launch_bounds__(256) void k_gemm2(const __bf16* __restrict__ h1,
                        const __bf16* __restrict__ W2T, __bf16* __restrict__ feat2, int M) {
  const int K = 256, Nn = 64;
  __shared__ __bf16 A_sm[128][40];
  __shared__ __bf16 B_sm[64][40];
  int tid = threadIdx.x;
  int lane = tid & 63, wid = tid >> 6;
  int wm = wid >> 1, wn = wid & 1;
  int bm = blockIdx.x * 128;

  int srow = tid >> 2;
  int scol = (tid & 3) * 8;

  f32x4 acc[4][2];
  #pragma unroll
  for (int i = 0; i < 4; ++i)
    #pragma unroll
    for (int j = 0; j < 2; ++j) acc[i][j] = (f32x4){0.f,0.f,0.f,0.f};

  for (int k0 = 0; k0 < K; k0 += 32) {
    #pragma unroll
    for (int p = 0; p < 2; ++p) {
      int row = p*64 + srow;
      bf16x8 v = (bf16x8){};
      if (bm + row < M) v = *(const bf16x8*)(h1 + (size_t)(bm+row)*K + k0 + scol);
      *(bf16x8*)&A_sm[row][scol] = v;
    }
    *(bf16x8*)&B_sm[srow][scol] = *(const bf16x8*)(W2T + (size_t)srow*K + k0 + scol);
    __syncthreads();
    bf16x8 af[4], bfr[2];
    #pragma unroll
    for (int mf = 0; mf < 4; ++mf)
      af[mf] = *(const bf16x8*)&A_sm[wm*64 + mf*16 + (lane&15)][(lane>>4)*8];
    #pragma unroll
    for (int nf = 0; nf < 2; ++nf)
      bfr[nf] = *(const bf16x8*)&B_sm[wn*32 + nf*16 + (lane&15)][(lane>>4)*8];
    #pragma unroll
    for (int mf = 0; mf < 4; ++mf)
      #pragma unroll
      for (int nf = 0; nf < 2; ++nf)
        acc[mf][nf] = __builtin_amdgcn_mfma_f32_16x16x32_bf16(af[mf], bfr[nf], acc[mf][nf], 0, 0, 0);
    __syncthreads();
  }
  #pragma unroll
  for (int mf = 0; mf < 4; ++mf) {
    #pragma unroll
    for (int j = 0; j < 4; ++j) {
      int m = bm + wm*64 + mf*16 + (lane>>4)*4 + j;
      if (m < M) {
        #pragma unroll
        for (int nf = 0; nf < 2; ++nf) {
          int n = wn*32 + nf*16 + (lane&15);
          feat2[(size_t)m*Nn + n] = (__bf16)acc[mf][nf][j];
        }
      }
    }
  }
}

// ---------------- attention logits layer 2 (bf16 feat2) ----------------
__global__ void k_lr2(const __bf16* __restrict__ feat2, const float* __restrict__ al,
                      const float* __restrict__ ar, float* __restrict__ el,
                      float* __restrict__ er, int Nn) {
  int v = blockIdx.x*4 + (threadIdx.x >> 6);
  int lane = threadIdx.x & 63;
  if (v >= Nn) return;
  float f = (float)feat2[(size_t)v*64 + lane];
  float pl = f * al[lane];
  float pr = f * ar[lane];
  #pragma unroll
  for (int m = 32; m >= 1; m >>= 1) {
    pl += __shfl_xor(pl, m);
    pr += __shfl_xor(pr, m);
  }
  if (lane == 0) { el[v] = pl; er[v] = pr; }
}

// ---------------- layer-1 softmax + aggregate + bias + ELU -> h1 (bf16) -------
// 1 block/node, wave h = head h. Half-wave 2-edge aggregation: lanes 0-31 edge j,
// lanes 32-63 edge j+1; each lane covers 2 channels via one dword load.
__global__ __launch_bounds__(256) void k_agg1(const __bf16* __restrict__ feat1,
                      const float* __restrict__ el, const float* __restrict__ er,
                      const int* __restrict__ row_start, const int* __restrict__ csr_src,
                      const float* __restrict__ b1, __bf16* __restrict__ h1, int Nn) {
  __shared__ float ex_sm[4][128];
  __shared__ int   s_sm[4][128];
  int v = blockIdx.x;
  int h = threadIdx.x >> 6, lane = threadIdx.x & 63;
  int half = lane >> 5;          // 0: even edges, 1: odd edges
  int d2 = (lane & 31) * 2;      // channel pair
  int r0 = row_start[v], deg = row_start[v+1] - r0;
  float erv = er[v*4 + h];
  float acc0 = 0.f, acc1 = 0.f;
  float inv = 0.f;
  if (deg <= 128) {
    float sm = 0.f;
    for (int i = lane; i < deg; i += 64) {
      int s = csr_src[r0+i];
      float e = LRELU(el[s*4 + h] + erv);
      float ex = __expf(e);
      ex_sm[h][i] = ex;
      s_sm[h][i] = s*256 + h*64;
      sm += ex;
    }
    #pragma unroll
    for (int m = 32; m >= 1; m >>= 1) sm += __shfl_xor(sm, m);
    inv = (deg > 0) ? 1.f/sm : 0.f;
    for (int j = 0; j < deg; j += 2) {
      int jj = j + half;
      if (jj < deg) {
        float w = ex_sm[h][jj];
        int sb = s_sm[h][jj];
        unsigned pv = *(const unsigned*)(feat1 + (size_t)sb + d2);
        acc0 = fmaf(bflo(pv), w, acc0);
        acc1 = fmaf(bfhi(pv), w, acc1);
      }
    }
  } else {
    float sm = 0.f;
    for (int i = lane; i < deg; i += 64) {
      int s = csr_src[r0+i];
      float e = LRELU(el[s*4 + h] + erv);
      sm += __expf(e);
    }
    #pragma unroll
    for (int m = 32; m >= 1; m >>= 1) sm += __shfl_xor(sm, m);
    inv = 1.f/sm;
    for (int c0 = 0; c0 < deg; c0 += 128) {
      int cnt = min(128, deg - c0);
      #pragma unroll
      for (int q = 0; q < 2; ++q) {
        int j = q*64 + lane;
        if (j < cnt) {
          int s = csr_src[r0 + c0 + j];
          float e = LRELU(el[s*4 + h] + erv);
          ex_sm[h][j] = __expf(e);
          s_sm[h][j] = s*256 + h*64;
        }
      }
      for (int j = 0; j < cnt; j += 2) {
        int jj = j + half;
        if (jj < cnt) {
          float w = ex_sm[h][jj];
          int sb = s_sm[h][jj];
          unsigned pv = *(const unsigned*)(feat1 + (size_t)sb + d2);
          acc0 = fmaf(bflo(pv), w, acc0);
          acc1 = fmaf(bfhi(pv), w, acc1);
        }
      }
    }
  }
  // combine the two edge-halves
  acc0 += __shfl_xor(acc0, 32);
  acc1 += __shfl_xor(acc1, 32);
  if (half == 0) {
    float v0 = acc0*inv + b1[h*64 + d2];
    float v1 = acc1*inv + b1[h*64 + d2 + 1];
    v0 = v0 > 0.f ? v0 : expm1f(v0);
    v1 = v1 > 0.f ? v1 : expm1f(v1);
    *(unsigned*)(h1 + (size_t)v*256 + h*64 + d2) = packbf(v0, v1);
  }
}

// ---------------- layer-2 softmax + aggregate + bias -> out (f32) ------------
// wave/node, same half-wave structure, bf16 feat2 gather.
__global__ __launch_bounds__(256) void k_agg2(const __bf16* __restrict__ feat2,
                      const float* __restrict__ el, const float* __restrict__ er,
                      const int* __restrict__ row_start, const int* __restrict__ csr_src,
                      const float* __restrict__ b2, float* __restrict__ out, int Nn) {
  __shared__ float ex_sm[4][128];
  __shared__ int   s_sm[4][128];
  int w = threadIdx.x >> 6;
  int v = blockIdx.x*4 + w;
  int lane = threadIdx.x & 63;
  int half = lane >> 5;
  int d2 = (lane & 31) * 2;
  if (v >= Nn) return;
  int r0 = row_start[v], deg = row_start[v+1] - r0;
  float erv = er[v];
  float acc0 = 0.f, acc1 = 0.f;
  float inv = 0.f;
  if (deg <= 128) {
    float sm = 0.f;
    for (int i = lane; i < deg; i += 64) {
      int s = csr_src[r0+i];
      float e = LRELU(el[s] + erv);
      float ex = __expf(e);
      ex_sm[w][i] = ex;
      s_sm[w][i] = s*64;
      sm += ex;
    }
    #pragma unroll
    for (int m = 32; m >= 1; m >>= 1) sm += __shfl_xor(sm, m);
    inv = (deg > 0) ? 1.f/sm : 0.f;
    for (int j = 0; j < deg; j += 2) {
      int jj = j + half;
      if (jj < deg) {
        float wt = ex_sm[w][jj];
        int sb = s_sm[w][jj];
        unsigned pv = *(const unsigned*)(feat2 + (size_t)sb + d2);
        acc0 = fmaf(bflo(pv), wt, acc0);
        acc1 = fmaf(bfhi(pv), wt, acc1);
      }
    }
  } else {
    float sm = 0.f;
    for (int i = lane; i < deg; i += 64) {
      int s = csr_src[r0+i];
      float e = LRELU(el[s] + erv);
      sm += __expf(e);
    }
    #pragma unroll
    for (int m = 32; m >= 1; m >>= 1) sm += __shfl_xor(sm, m);
    inv = 1.f/sm;
    for (int c0 = 0; c0 < deg; c0 += 128) {
      int cnt = min(128, deg - c0);
      #pragma unroll
      for (int q = 0; q < 2; ++q) {
        int j = q*64 + lane;
        if (j < cnt) {
          int s = csr_src[r0 + c0 + j];
          float e = LRELU(el[s] + erv);
          ex_sm[w][j] = __expf(e);
          s_sm[w][j] = s*64;
        }
      }
      for (int j = 0; j < cnt; j += 2) {
        int jj = j + half;
        if (jj < cnt) {
          float wt = ex_sm[w][jj];
          int sb = s_sm[w][jj];
          unsigned pv = *(const unsigned*)(feat2 + (size_t)sb + d2);
          acc0 = fmaf(bflo(pv), wt, acc0);
          acc1 = fmaf(bfhi(pv), wt, acc1);
        }
      }
    }
  }
  acc0 += __shfl_xor(acc0, 32);
  acc1 += __shfl_xor(acc1, 32);
  if (half == 0) {
    float v0 = acc0*inv + b2[d2];
    float v1 = acc1*inv + b2[d2 + 1];
    *(float2*)(out + (size_t)v*64 + d2) = make_float2(v0, v1);
  }
}

extern "C" void kernel_launch(void* const* d_in, const int* in_sizes, int n_in,
                              void* d_out, int out_size, void* d_ws, size_t ws_size,
                              hipStream_t stream) {
  const float* x   = (const float*)d_in[0];
  const int*   src = (const int*)d_in[1];
  const int*   dst = (const int*)d_in[2];
  const float* W1  = (const float*)d_in[3];
  const float* al1 = (const float*)d_in[4];
  const float* ar1 = (const float*)d_in[5];
  const float* b1  = (const float*)d_in[6];
  const float* W2  = (const float*)d_in[7];
  const float* al2 = (const float*)d_in[8];
  const float* ar2 = (const float*)d_in[9];
  const float* b2  = (const float*)d_in[10];
  float* out = (float*)d_out;

  const int N = in_sizes[0] / 512;
  const int E = in_sizes[1];

  char* p = (char*)d_ws;
  auto alloc = [&](size_t bytes) {
    char* r = p; p += (bytes + 255) & ~(size_t)255; return r;
  };
  __bf16* feat1   = (__bf16*)alloc((size_t)N*256*sizeof(__bf16));
  __bf16* h1      = (__bf16*)alloc((size_t)N*256*sizeof(__bf16));
  __bf16* feat2   = (__bf16*)alloc((size_t)N*64*sizeof(__bf16));
  float* el1      = (float*)alloc((size_t)N*4*sizeof(float));
  float* er1      = (float*)alloc((size_t)N*4*sizeof(float));
  float* el2      = (float*)alloc((size_t)N*sizeof(float));
  float* er2      = (float*)alloc((size_t)N*sizeof(float));
  int*   deg      = (int*)alloc((size_t)N*sizeof(int));
  int*   row_start= (int*)alloc((size_t)(N+1)*sizeof(int));
  int*   cursor   = (int*)alloc((size_t)N*sizeof(int));
  int*   bsums    = (int*)alloc(64*sizeof(int));
  int*   csr_src  = (int*)alloc((size_t)E*sizeof(int));
  __bf16* w1t     = (__bf16*)alloc((size_t)256*512*sizeof(__bf16));
  __bf16* w2t     = (__bf16*)alloc((size_t)64*256*sizeof(__bf16));

  hipMemsetAsync(deg, 0, (size_t)N*sizeof(int), stream);
  hipMemsetAsync(cursor, 0, (size_t)N*sizeof(int), stream);

  k_hist<<<(E+255)/256, 256, 0, stream>>>(dst, deg, E);
  int nb = (N + 1023)/1024;
  k_scan1<<<nb, 1024, 0, stream>>>(deg, row_start, bsums, N);
  k_scan2<<<1, 64, 0, stream>>>(bsums, nb);
  k_scan3<<<nb, 1024, 0, stream>>>(row_start, bsums, N);
  k_fill<<<(E+255)/256, 256, 0, stream>>>(src, dst, row_start, cursor, csr_src, E);
  k_w1t<<<(256*512+255)/256, 256, 0, stream>>>(W1, w1t);
  k_w2t<<<(64*256+255)/256, 256, 0, stream>>>(W2, w2t);

  k_gemm1<<<(N+63)/64, 256, 0, stream>>>(x, w1t, feat1, al1, ar1, el1, er1, N);
  k_agg1<<<N, 256, 0, stream>>>(feat1, el1, er1, row_start, csr_src, b1, h1, N);
  k_gemm2<<<(N+127)/128, 256, 0, stream>>>(h1, w2t, feat2, N);
  k_lr2<<<(N+3)/4, 256, 0, stream>>>(feat2, al2, ar2, el2, er2, N);
  k_agg2<<<(N+3)/4, 256, 0, stream>>>(feat2, el2, er2, row_start, csr_src, b2, out, N);
}

// Round 9
// 301.439 us; speedup vs baseline: 1.1188x; 1.1188x over previous
//
#include <hip/hip_runtime.h>
#include <cmath>

#define LRELU(e) ((e) > 0.f ? (e) : 0.2f*(e))

typedef __bf16 bf16x8 __attribute__((ext_vector_type(8)));
typedef float  f32x4  __attribute__((ext_vector_type(4)));

// ---------------- CSR build ----------------
__global__ void k_hist(const int* __restrict__ dst, int* __restrict__ deg, int E) {
  int e = blockIdx.x*blockDim.x + threadIdx.x;
  if (e < E) atomicAdd(&deg[dst[e]], 1);
}

__global__ __launch_bounds__(1024) void k_scan1(const int* __restrict__ deg,
                        int* __restrict__ row_start, int* __restrict__ bsums, int n) {
  __shared__ int sm[1024];
  int t = threadIdx.x;
  int i = blockIdx.x*1024 + t;
  sm[t] = (i < n) ? deg[i] : 0;
  __syncthreads();
  for (int off = 1; off < 1024; off <<= 1) {
    int v = (t >= off) ? sm[t-off] : 0;
    __syncthreads();
    sm[t] += v;
    __syncthreads();
  }
  if (i < n) row_start[i+1] = sm[t];
  if (t == 1023) bsums[blockIdx.x] = sm[1023];
  if (i == 0) row_start[0] = 0;
}

__global__ void k_scan2(int* __restrict__ bsums, int nb) {
  __shared__ int sm[64];
  int t = threadIdx.x;
  sm[t] = (t < nb) ? bsums[t] : 0;
  __syncthreads();
  for (int off = 1; off < 64; off <<= 1) {
    int v = (t >= off) ? sm[t-off] : 0;
    __syncthreads();
    sm[t] += v;
    __syncthreads();
  }
  if (t < nb) bsums[t] = (t == 0) ? 0 : sm[t-1];
}

__global__ __launch_bounds__(1024) void k_scan3(int* __restrict__ row_start,
                        const int* __restrict__ bsums, int n) {
  int i = blockIdx.x*1024 + threadIdx.x;
  if (i < n) row_start[i+1] += bsums[blockIdx.x];
}

__global__ void k_fill(const int* __restrict__ src, const int* __restrict__ dst,
                       const int* __restrict__ row_start, int* __restrict__ cursor,
                       int* __restrict__ csr_src, int E) {
  int e = blockIdx.x*blockDim.x + threadIdx.x;
  if (e < E) {
    int d = dst[e];
    int pos = atomicAdd(&cursor[d], 1);
    csr_src[row_start[d] + pos] = src[e];
  }
}

// ---------------- weight transposes to bf16 ----------------
__global__ void k_w1t(const float* __restrict__ W1, __bf16* __restrict__ W1T) {
  int idx = blockIdx.x*blockDim.x + threadIdx.x;   // n*512 + k
  if (idx < 256*512) {
    int n = idx >> 9, k = idx & 511;
    W1T[idx] = (__bf16)W1[k*256 + n];
  }
}

__global__ void k_w2t(const float* __restrict__ W2, __bf16* __restrict__ W2T) {
  int idx = blockIdx.x*blockDim.x + threadIdx.x;   // n*256 + k
  if (idx < 64*256) {
    int n = idx >> 8, k = idx & 255;
    W2T[idx] = (__bf16)W2[k*64 + n];
  }
}

// ---------------- GEMM1 (bf16 MFMA) + fused lr1, bf16 feat1 out ----------------
// feat1[N,256] = x[N,512] @ W1[512,256]. BM=64, BN=256 (x read ONCE), BK=32.
// 4 waves (2x2): wave tile 32 rows x 128 cols (= 2 heads).
__global__ __launch_bounds__(256) void k_gemm1(const float* __restrict__ x,
                        const __bf16* __restrict__ W1T, __bf16* __restrict__ feat1,
                        const float* __restrict__ al1, const float* __restrict__ ar1,
                        float* __restrict__ el1, float* __restrict__ er1, int M) {
  const int K = 512, Nn = 256;
  __shared__ __bf16 A_sm[64][40];
  __shared__ __bf16 B_sm[256][40];
  int tid = threadIdx.x;
  int lane = tid & 63, wid = tid >> 6;
  int wm = wid >> 1, wn = wid & 1;
  int bm = blockIdx.x * 64;

  int srow = tid >> 2;            // 0..63
  int scol = (tid & 3) * 8;       // 0,8,16,24

  f32x4 acc[2][8];
  #pragma unroll
  for (int i = 0; i < 2; ++i)
    #pragma unroll
    for (int j = 0; j < 8; ++j) acc[i][j] = (f32x4){0.f,0.f,0.f,0.f};

  for (int k0 = 0; k0 < K; k0 += 32) {
    // stage A: x[bm+srow][k0+scol..+8] f32 -> bf16
    {
      bf16x8 v;
      if (bm + srow < M) {
        const float* xp = x + (size_t)(bm+srow)*K + k0 + scol;
        float4 f0 = *(const float4*)xp;
        float4 f1 = *(const float4*)(xp+4);
        v[0]=(__bf16)f0.x; v[1]=(__bf16)f0.y; v[2]=(__bf16)f0.z; v[3]=(__bf16)f0.w;
        v[4]=(__bf16)f1.x; v[5]=(__bf16)f1.y; v[6]=(__bf16)f1.z; v[7]=(__bf16)f1.w;
      } else {
        v = (bf16x8){};
      }
      *(bf16x8*)&A_sm[srow][scol] = v;
    }
    // stage B: W1T rows 0..255
    #pragma unroll
    for (int p = 0; p < 4; ++p) {
      int row = p*64 + srow;
      *(bf16x8*)&B_sm[row][scol] = *(const bf16x8*)(W1T + (size_t)row*K + k0 + scol);
    }
    __syncthreads();
    bf16x8 af[2], bfr[8];
    #pragma unroll
    for (int mf = 0; mf < 2; ++mf)
      af[mf] = *(const bf16x8*)&A_sm[wm*32 + mf*16 + (lane&15)][(lane>>4)*8];
    #pragma unroll
    for (int nf = 0; nf < 8; ++nf)
      bfr[nf] = *(const bf16x8*)&B_sm[wn*128 + nf*16 + (lane&15)][(lane>>4)*8];
    #pragma unroll
    for (int mf = 0; mf < 2; ++mf)
      #pragma unroll
      for (int nf = 0; nf < 8; ++nf)
        acc[mf][nf] = __builtin_amdgcn_mfma_f32_16x16x32_bf16(af[mf], bfr[nf], acc[mf][nf], 0, 0, 0);
    __syncthreads();
  }
  // attn weight slices: index == output column
  float al_r[8], ar_r[8];
  #pragma unroll
  for (int nf = 0; nf < 8; ++nf) {
    int n = wn*128 + nf*16 + (lane&15);
    al_r[nf] = al1[n];
    ar_r[nf] = ar1[n];
  }
  #pragma unroll
  for (int mf = 0; mf < 2; ++mf) {
    #pragma unroll
    for (int j = 0; j < 4; ++j) {
      int m = bm + wm*32 + mf*16 + (lane>>4)*4 + j;
      float pl[2] = {0.f, 0.f}, pr[2] = {0.f, 0.f};
      #pragma unroll
      for (int nf = 0; nf < 8; ++nf) {
        float val = acc[mf][nf][j];
        int g = nf >> 2;
        pl[g] = fmaf(val, al_r[nf], pl[g]);
        pr[g] = fmaf(val, ar_r[nf], pr[g]);
        if (m < M) {
          int n = wn*128 + nf*16 + (lane&15);
          feat1[(size_t)m*Nn + n] = (__bf16)val;
        }
      }
      #pragma unroll
      for (int g = 0; g < 2; ++g) {
        #pragma unroll
        for (int s = 8; s >= 1; s >>= 1) {
          pl[g] += __shfl_xor(pl[g], s);
          pr[g] += __shfl_xor(pr[g], s);
        }
      }
      if ((lane & 15) == 0 && m < M) {
        el1[m*4 + wn*2 + 0] = pl[0];
        er1[m*4 + wn*2 + 0] = pr[0];
        el1[m*4 + wn*2 + 1] = pl[1];
        er1[m*4 + wn*2 + 1] = pr[1];
      }
    }
  }
}

// ---------------- GEMM2 (bf16 MFMA): feat2[N,64] = h1[N,256] @ W2[256,64] -----
// BM=128, BN=64, BK=32; bf16 output.
__global__ __launch_bounds__(256) void k_gemm2(const __bf16* __restrict__ h1,
                        const __bf16* __restrict__ W2T, __bf16* __restrict__ feat2, int M) {
  const int K = 256, Nn = 64;
  __shared__ __bf16 A_sm[128][40];
  __shared__ __bf16 B_sm[64][40];
  int tid = threadIdx.x;
  int lane = tid & 63, wid = tid >> 6;
  int wm = wid >> 1, wn = wid & 1;
  int bm = blockIdx.x * 128;

  int srow = tid >> 2;
  int scol = (tid & 3) * 8;

  f32x4 acc[4][2];
  #pragma unroll
  for (int i = 0; i < 4; ++i)
    #pragma unroll
    for (int j = 0; j < 2; ++j) acc[i][j] = (f32x4){0.f,0.f,0.f,0.f};

  for (int k0 = 0; k0 < K; k0 += 32) {
    #pragma unroll
    for (int p = 0; p < 2; ++p) {
      int row = p*64 + srow;
      bf16x8 v = (bf16x8){};
      if (bm + row < M) v = *(const bf16x8*)(h1 + (size_t)(bm+row)*K + k0 + scol);
      *(bf16x8*)&A_sm[row][scol] = v;
    }
    *(bf16x8*)&B_sm[srow][scol] = *(const bf16x8*)(W2T + (size_t)srow*K + k0 + scol);
    __syncthreads();
    bf16x8 af[4], bfr[2];
    #pragma unroll
    for (int mf = 0; mf < 4; ++mf)
      af[mf] = *(const bf16x8*)&A_sm[wm*64 + mf*16 + (lane&15)][(lane>>4)*8];
    #pragma unroll
    for (int nf = 0; nf < 2; ++nf)
      bfr[nf] = *(const bf16x8*)&B_sm[wn*32 + nf*16 + (lane&15)][(lane>>4)*8];
    #pragma unroll
    for (int mf = 0; mf < 4; ++mf)
      #pragma unroll
      for (int nf = 0; nf < 2; ++nf)
        acc[mf][nf] = __builtin_amdgcn_mfma_f32_16x16x32_bf16(af[mf], bfr[nf], acc[mf][nf], 0, 0, 0);
    __syncthreads();
  }
  #pragma unroll
  for (int mf = 0; mf < 4; ++mf) {
    #pragma unroll
    for (int j = 0; j < 4; ++j) {
      int m = bm + wm*64 + mf*16 + (lane>>4)*4 + j;
      if (m < M) {
        #pragma unroll
        for (int nf = 0; nf < 2; ++nf) {
          int n = wn*32 + nf*16 + (lane&15);
          feat2[(size_t)m*Nn + n] = (__bf16)acc[mf][nf][j];
        }
      }
    }
  }
}

// ---------------- attention logits layer 2 (bf16 feat2) ----------------
__global__ void k_lr2(const __bf16* __restrict__ feat2, const float* __restrict__ al,
                      const float* __restrict__ ar, float* __restrict__ el,
                      float* __restrict__ er, int Nn) {
  int v = blockIdx.x*4 + (threadIdx.x >> 6);
  int lane = threadIdx.x & 63;
  if (v >= Nn) return;
  float f = (float)feat2[(size_t)v*64 + lane];
  float pl = f * al[lane];
  float pr = f * ar[lane];
  #pragma unroll
  for (int m = 32; m >= 1; m >>= 1) {
    pl += __shfl_xor(pl, m);
    pr += __shfl_xor(pr, m);
  }
  if (lane == 0) { el[v] = pl; er[v] = pr; }
}

// ---------------- layer-1 softmax + aggregate + bias + ELU -> h1 (bf16) -------
// 1 block/node, wave h = head h. Full-wave (64 lanes = 64 channels), one edge
// per iteration; LDS arrays padded with 4 zero-weight safe entries so the main
// loop is guard-free; global gather software-pipelined depth 2.
__global__ __launch_bounds__(256) void k_agg1(const __bf16* __restrict__ feat1,
                      const float* __restrict__ el, const float* __restrict__ er,
                      const int* __restrict__ row_start, const int* __restrict__ csr_src,
                      const float* __restrict__ b1, __bf16* __restrict__ h1, int Nn) {
  __shared__ float ex_sm[4][136];
  __shared__ int   s_sm[4][136];
  int v = blockIdx.x;
  int h = threadIdx.x >> 6, lane = threadIdx.x & 63;
  int r0 = row_start[v], deg = row_start[v+1] - r0;
  if (deg == 0) {
    float val = b1[h*64 + lane];
    val = val > 0.f ? val : expm1f(val);
    h1[(size_t)v*256 + h*64 + lane] = (__bf16)val;
    return;
  }
  float erv = er[v*4 + h];
  const unsigned short* f16 = (const unsigned short*)feat1;
  float acc = 0.f;
  float inv = 0.f;
  if (deg <= 128) {
    float sm = 0.f;
    for (int i = lane; i < deg; i += 64) {
      int s = csr_src[r0+i];
      float e = LRELU(el[s*4 + h] + erv);
      float ex = __expf(e);
      ex_sm[h][i] = ex;
      s_sm[h][i] = s*256 + h*64;
      sm += ex;
    }
    if (lane < 4) { ex_sm[h][deg+lane] = 0.f; s_sm[h][deg+lane] = 0; }
    #pragma unroll
    for (int m = 32; m >= 1; m >>= 1) sm += __shfl_xor(sm, m);
    inv = 1.f/sm;
    // depth-2 pipelined gather (pads make j+2 loads safe)
    unsigned short u0 = f16[(size_t)(s_sm[h][0] + lane)];
    unsigned short u1 = f16[(size_t)(s_sm[h][1] + lane)];
    for (int j = 0; j < deg; ++j) {
      unsigned short u2 = f16[(size_t)(s_sm[h][j+2] + lane)];
      acc = fmaf(__uint_as_float((unsigned)u0 << 16), ex_sm[h][j], acc);
      u0 = u1; u1 = u2;
    }
  } else {
    float sm = 0.f;
    for (int i = lane; i < deg; i += 64) {
      int s = csr_src[r0+i];
      float e = LRELU(el[s*4 + h] + erv);
      sm += __expf(e);
    }
    #pragma unroll
    for (int m = 32; m >= 1; m >>= 1) sm += __shfl_xor(sm, m);
    inv = 1.f/sm;
    for (int c0 = 0; c0 < deg; c0 += 128) {
      int cnt = min(128, deg - c0);
      #pragma unroll
      for (int q = 0; q < 2; ++q) {
        int j = q*64 + lane;
        if (j < cnt) {
          int s = csr_src[r0 + c0 + j];
          float e = LRELU(el[s*4 + h] + erv);
          ex_sm[h][j] = __expf(e);
          s_sm[h][j] = s*256 + h*64;
        }
      }
      for (int j = 0; j < cnt; ++j) {
        acc = fmaf(__uint_as_float((unsigned)f16[(size_t)(s_sm[h][j] + lane)] << 16),
                   ex_sm[h][j], acc);
      }
    }
  }
  float val = acc*inv + b1[h*64 + lane];
  val = val > 0.f ? val : expm1f(val);
  h1[(size_t)v*256 + h*64 + lane] = (__bf16)val;
}

// ---------------- layer-2 softmax + aggregate + bias -> out (f32) ------------
// wave per node (H=1, D=64), same padded + pipelined structure.
__global__ __launch_bounds__(256) void k_agg2(const __bf16* __restrict__ feat2,
                      const float* __restrict__ el, const float* __restrict__ er,
                      const int* __restrict__ row_start, const int* __restrict__ csr_src,
                      const float* __restrict__ b2, float* __restrict__ out, int Nn) {
  __shared__ float ex_sm[4][136];
  __shared__ int   s_sm[4][136];
  int w = threadIdx.x >> 6;
  int v = blockIdx.x*4 + w;
  int lane = threadIdx.x & 63;
  if (v >= Nn) return;
  int r0 = row_start[v], deg = row_start[v+1] - r0;
  if (deg == 0) {
    out[(size_t)v*64 + lane] = b2[lane];
    return;
  }
  float erv = er[v];
  const unsigned short* f16 = (const unsigned short*)feat2;
  float acc = 0.f;
  float inv = 0.f;
  if (deg <= 128) {
    float sm = 0.f;
    for (int i = lane; i < deg; i += 64) {
      int s = csr_src[r0+i];
      float e = LRELU(el[s] + erv);
      float ex = __expf(e);
      ex_sm[w][i] = ex;
      s_sm[w][i] = s*64;
      sm += ex;
    }
    if (lane < 4) { ex_sm[w][deg+lane] = 0.f; s_sm[w][deg+lane] = 0; }
    #pragma unroll
    for (int m = 32; m >= 1; m >>= 1) sm += __shfl_xor(sm, m);
    inv = 1.f/sm;
    unsigned short u0 = f16[(size_t)(s_sm[w][0] + lane)];
    unsigned short u1 = f16[(size_t)(s_sm[w][1] + lane)];
    for (int j = 0; j < deg; ++j) {
      unsigned short u2 = f16[(size_t)(s_sm[w][j+2] + lane)];
      acc = fmaf(__uint_as_float((unsigned)u0 << 16), ex_sm[w][j], acc);
      u0 = u1; u1 = u2;
    }
  } else {
    float sm = 0.f;
    for (int i = lane; i < deg; i += 64) {
      int s = csr_src[r0+i];
      float e = LRELU(el[s] + erv);
      sm += __expf(e);
    }
    #pragma unroll
    for (int m = 32; m >= 1; m >>= 1) sm += __shfl_xor(sm, m);
    inv = 1.f/sm;
    for (int c0 = 0; c0 < deg; c0 += 128) {
      int cnt = min(128, deg - c0);
      #pragma unroll
      for (int q = 0; q < 2; ++q) {
        int j = q*64 + lane;
        if (j < cnt) {
          int s = csr_src[r0 + c0 + j];
          float e = LRELU(el[s] + erv);
          ex_sm[w][j] = __expf(e);
          s_sm[w][j] = s*64;
        }
      }
      for (int j = 0; j < cnt; ++j) {
        acc = fmaf(__uint_as_float((unsigned)f16[(size_t)(s_sm[w][j] + lane)] << 16),
                   ex_sm[w][j], acc);
      }
    }
  }
  out[(size_t)v*64 + lane] = acc*inv + b2[lane];
}

extern "C" void kernel_launch(void* const* d_in, const int* in_sizes, int n_in,
                              void* d_out, int out_size, void* d_ws, size_t ws_size,
                              hipStream_t stream) {
  const float* x   = (const float*)d_in[0];
  const int*   src = (const int*)d_in[1];
  const int*   dst = (const int*)d_in[2];
  const float* W1  = (const float*)d_in[3];
  const float* al1 = (const float*)d_in[4];
  const float* ar1 = (const float*)d_in[5];
  const float* b1  = (const float*)d_in[6];
  const float* W2  = (const float*)d_in[7];
  const float* al2 = (const float*)d_in[8];
  const float* ar2 = (const float*)d_in[9];
  const float* b2  = (const float*)d_in[10];
  float* out = (float*)d_out;

  const int N = in_sizes[0] / 512;
  const int E = in_sizes[1];

  char* p = (char*)d_ws;
  auto alloc = [&](size_t bytes) {
    char* r = p; p += (bytes + 255) & ~(size_t)255; return r;
  };
  __bf16* feat1   = (__bf16*)alloc((size_t)N*256*sizeof(__bf16));
  __bf16* h1      = (__bf16*)alloc((size_t)N*256*sizeof(__bf16));
  __bf16* feat2   = (__bf16*)alloc((size_t)N*64*sizeof(__bf16));
  float* el1      = (float*)alloc((size_t)N*4*sizeof(float));
  float* er1      = (float*)alloc((size_t)N*4*sizeof(float));
  float* el2      = (float*)alloc((size_t)N*sizeof(float));
  float* er2      = (float*)alloc((size_t)N*sizeof(float));
  int*   deg      = (int*)alloc((size_t)N*sizeof(int));
  int*   row_start= (int*)alloc((size_t)(N+1)*sizeof(int));
  int*   cursor   = (int*)alloc((size_t)N*sizeof(int));
  int*   bsums    = (int*)alloc(64*sizeof(int));
  int*   csr_src  = (int*)alloc((size_t)E*sizeof(int));
  __bf16* w1t     = (__bf16*)alloc((size_t)256*512*sizeof(__bf16));
  __bf16* w2t     = (__bf16*)alloc((size_t)64*256*sizeof(__bf16));

  hipMemsetAsync(deg, 0, (size_t)N*sizeof(int), stream);
  hipMemsetAsync(cursor, 0, (size_t)N*sizeof(int), stream);

  k_hist<<<(E+255)/256, 256, 0, stream>>>(dst, deg, E);
  int nb = (N + 1023)/1024;
  k_scan1<<<nb, 1024, 0, stream>>>(deg, row_start, bsums, N);
  k_scan2<<<1, 64, 0, stream>>>(bsums, nb);
  k_scan3<<<nb, 1024, 0, stream>>>(row_start, bsums, N);
  k_fill<<<(E+255)/256, 256, 0, stream>>>(src, dst, row_start, cursor, csr_src, E);
  k_w1t<<<(256*512+255)/256, 256, 0, stream>>>(W1, w1t);
  k_w2t<<<(64*256+255)/256, 256, 0, stream>>>(W2, w2t);

  k_gemm1<<<(N+63)/64, 256, 0, stream>>>(x, w1t, feat1, al1, ar1, el1, er1, N);
  k_agg1<<<N, 256, 0, stream>>>(feat1, el1, er1, row_start, csr_src, b1, h1, N);
  k_gemm2<<<(N+127)/128, 256, 0, stream>>>(h1, w2t, feat2, N);
  k_lr2<<<(N+3)/4, 256, 0, stream>>>(feat2, al2, ar2, el2, er2, N);
  k_agg2<<<(N+3)/4, 256, 0, stream>>>(feat2, el2, er2, row_start, csr_src, b2, out, N);
}